// Round 3
// baseline (366.767 us; speedup 1.0000x reference)
//
#include <hip/hip_runtime.h>

// Problem constants (from reference):
//  x: [16384,16,128] f32; w_q/k/v: [4,128,32] f32; w_o: [4,32,128] f32
//  out: [16384,16,128] f32
#define BATCHES 16384
#define BPW     8               // batches per workgroup
#define NWG     (BATCHES / BPW) // 2048 workgroups, 256 threads each

typedef __attribute__((ext_vector_type(8))) _Float16 h8;
typedef __attribute__((ext_vector_type(4))) float f4;

#define MFMA16(a, b, c) __builtin_amdgcn_mfma_f32_16x16x32_f16((a), (b), (c), 0, 0, 0)

__device__ __forceinline__ h8 h8_zero() {
  h8 v;
#pragma unroll
  for (int j = 0; j < 8; ++j) v[j] = (_Float16)0.0f;
  return v;
}

__global__ __launch_bounds__(256, 1)
void attn16(const float* __restrict__ xg,
            const float* __restrict__ wq,
            const float* __restrict__ wk,
            const float* __restrict__ wv,
            const float* __restrict__ wo,
            float* __restrict__ outg)
{
  // LDS: 34 KB total (single-buffered x: the step-7 barrier already
  // separates all step-2 reads from step-8 writes, so dbuf was redundant)
  __shared__ __align__(16) _Float16 s_xh[2048];     // x hi, [16][128], swizzled
  __shared__ __align__(16) _Float16 s_xl[2048];     // x lo
  __shared__ __align__(16) float    s_qk[4][1024];  // per-wave Q[16][32] f32 (0..511), K (512..1023), swizzled
  __shared__ __align__(16) _Float16 s_vt[4][512];   // per-wave Vt[32][16] = V^T
  __shared__ __align__(16) _Float16 s_a [4][256];   // per-wave A[16][16]
  __shared__ __align__(16) _Float16 s_h [2048];     // Hcat [16][128], swizzled

  const int tid  = threadIdx.x;
  const int wid  = tid >> 6;   // wave id == head id == out-col-slice id
  const int lane = tid & 63;
  const int lhi  = lane >> 4;  // 0..3
  const int llo  = lane & 15;  // 0..15

  // ---------------- resident weight B-fragments ----------------
  // B-frag layout: lane holds B[k=(lane>>4)*8+j][n=ntile*16+(lane&15)], j=0..7
  h8 wqh[4][2], wql[4][2], wkh[4][2], wkl[4][2], wvf[4][2], wof[4][2];
#pragma unroll
  for (int ks = 0; ks < 4; ++ks) {
#pragma unroll
    for (int nt = 0; nt < 2; ++nt) {
#pragma unroll
      for (int j = 0; j < 8; ++j) {
        const int e = ks * 32 + lhi * 8 + j;   // embed index 0..127
        const int d = nt * 16 + llo;           // head-dim col 0..31
        const float q = wq[(size_t)wid * 4096 + e * 32 + d];
        const float k = wk[(size_t)wid * 4096 + e * 32 + d];
        const float v = wv[(size_t)wid * 4096 + e * 32 + d];
        const _Float16 qh = (_Float16)q;
        const _Float16 kh = (_Float16)k;
        wqh[ks][nt][j] = qh;
        wql[ks][nt][j] = (_Float16)(q - (float)qh);
        wkh[ks][nt][j] = kh;
        wkl[ks][nt][j] = (_Float16)(k - (float)kh);
        wvf[ks][nt][j] = (_Float16)v;
        // w_o as B[k=h*32+d][n=o], slice n = wid*32..wid*32+31; kstep ks == head
        const int o = wid * 32 + nt * 16 + llo;
        wof[ks][nt][j] = (_Float16)wo[(size_t)ks * 4096 + (lhi * 8 + j) * 128 + o];
      }
    }
  }

  const int b0 = blockIdx.x * BPW;
  const float scale = 0.17677669529663687f;  // 32^-0.5

  // ---------------- prologue: stage batch b0 ----------------
  {
    const float4* src = (const float4*)(xg + (size_t)b0 * 2048);
    const float4 a = src[tid * 2 + 0];
    const float4 b = src[tid * 2 + 1];
    const int m  = tid >> 4;                 // seq row 0..15
    const int sl = (tid & 15) ^ (m & 7);     // swizzled 8-elem slot
    const float f[8] = {a.x, a.y, a.z, a.w, b.x, b.y, b.z, b.w};
    h8 hi, lo;
#pragma unroll
    for (int j = 0; j < 8; ++j) {
      const _Float16 h = (_Float16)f[j];
      hi[j] = h;
      lo[j] = (_Float16)(f[j] - (float)h);
    }
    *(h8*)&s_xh[m * 128 + sl * 8] = hi;
    *(h8*)&s_xl[m * 128 + sl * 8] = lo;
  }
  __syncthreads();

  for (int bi = 0; bi < BPW; ++bi) {
    const int b = b0 + bi;

    // 1. issue prefetch loads for next batch (consumed at step 8)
    float4 pa = {}, pb = {};
    const bool hasNext = (bi + 1 < BPW);
    if (hasNext) {
      const float4* src = (const float4*)(xg + (size_t)(b + 1) * 2048);
      pa = src[tid * 2 + 0];
      pb = src[tid * 2 + 1];
    }

    // 2. QKV projections. x A-frags from LDS (hi/lo); Q,K split-precision (3 products), V plain.
    f4 qacc[2] = {{0,0,0,0},{0,0,0,0}};
    f4 kacc[2] = {{0,0,0,0},{0,0,0,0}};
    f4 vacc[2] = {{0,0,0,0},{0,0,0,0}};
#pragma unroll
    for (int ks = 0; ks < 4; ++ks) {
      const int sl = (ks * 4 + lhi) ^ (llo & 7);
      const h8 ah = *(const h8*)&s_xh[llo * 128 + sl * 8];
      const h8 al = *(const h8*)&s_xl[llo * 128 + sl * 8];
#pragma unroll
      for (int nt = 0; nt < 2; ++nt) {
        qacc[nt] = MFMA16(ah, wqh[ks][nt], qacc[nt]);
        qacc[nt] = MFMA16(ah, wql[ks][nt], qacc[nt]);
        qacc[nt] = MFMA16(al, wqh[ks][nt], qacc[nt]);
        kacc[nt] = MFMA16(ah, wkh[ks][nt], kacc[nt]);
        kacc[nt] = MFMA16(ah, wkl[ks][nt], kacc[nt]);
        kacc[nt] = MFMA16(al, wkh[ks][nt], kacc[nt]);
        vacc[nt] = MFMA16(ah, wvf[ks][nt], vacc[nt]);
      }
    }

    // 3. bounce Q,K (f32, swizzled) and Vt (=V^T, f16) through per-wave LDS
    float* qb = s_qk[wid];
#pragma unroll
    for (int nt = 0; nt < 2; ++nt) {
#pragma unroll
      for (int r = 0; r < 4; ++r) {
        const int t = lhi * 4 + r;        // seq row (C layout: row=(lane>>4)*4+reg)
        const int d = nt * 16 + llo;      // head-dim col (C layout: col=lane&15)
        const int sl = (d >> 2) ^ (t & 7);
        qb[t * 32 + sl * 4 + (d & 3)]       = qacc[nt][r];
        qb[512 + t * 32 + sl * 4 + (d & 3)] = kacc[nt][r];
        s_vt[wid][d * 16 + t] = (_Float16)vacc[nt][r];   // Vt[d][t']
      }
    }

    // 4. re-fragment Q (A-side) and K (B-side) with hi/lo split; scores = 3 MFMAs
    h8 qhf, qlf, khf, klf;
    {
      const int s0 = (lhi * 2 + 0) ^ (llo & 7);
      const int s1 = (lhi * 2 + 1) ^ (llo & 7);
      const f4 qa = *(const f4*)&qb[llo * 32 + s0 * 4];
      const f4 qc = *(const f4*)&qb[llo * 32 + s1 * 4];
      const f4 ka = *(const f4*)&qb[512 + llo * 32 + s0 * 4];
      const f4 kc = *(const f4*)&qb[512 + llo * 32 + s1 * 4];
#pragma unroll
      for (int j = 0; j < 4; ++j) {
        _Float16 h;
        h = (_Float16)qa[j]; qhf[j]     = h; qlf[j]     = (_Float16)(qa[j] - (float)h);
        h = (_Float16)qc[j]; qhf[4 + j] = h; qlf[4 + j] = (_Float16)(qc[j] - (float)h);
        h = (_Float16)ka[j]; khf[j]     = h; klf[j]     = (_Float16)(ka[j] - (float)h);
        h = (_Float16)kc[j]; khf[4 + j] = h; klf[4 + j] = (_Float16)(kc[j] - (float)h);
      }
    }
    f4 sacc = {0,0,0,0};
    sacc = MFMA16(qhf, khf, sacc);
    sacc = MFMA16(qhf, klf, sacc);
    sacc = MFMA16(qlf, khf, sacc);

    // 5. softmax (f32, wave-parallel across the 16-lane row groups), write A (f16)
#pragma unroll
    for (int r = 0; r < 4; ++r) {
      const float v = sacc[r] * scale;
      float mx = v;
      mx = fmaxf(mx, __shfl_xor(mx, 1));
      mx = fmaxf(mx, __shfl_xor(mx, 2));
      mx = fmaxf(mx, __shfl_xor(mx, 4));
      mx = fmaxf(mx, __shfl_xor(mx, 8));
      const float p = __expf(v - mx);
      float sm = p;
      sm += __shfl_xor(sm, 1);
      sm += __shfl_xor(sm, 2);
      sm += __shfl_xor(sm, 4);
      sm += __shfl_xor(sm, 8);
      const float a = p * __builtin_amdgcn_rcpf(sm);
      const int t = lhi * 4 + r;
      s_a[wid][t * 16 + llo] = (_Float16)a;   // A[s][t']
    }

    // 6. H = A @ V via 16x16x32 with zero-padded k>=16 (lanes lhi>=2 supply zeros)
    h8 af = h8_zero(), v0f = h8_zero(), v1f = h8_zero();
    if (lhi < 2) {
      af  = *(const h8*)&s_a[wid][llo * 16 + lhi * 8];
      v0f = *(const h8*)&s_vt[wid][(0  + llo) * 16 + lhi * 8];
      v1f = *(const h8*)&s_vt[wid][(16 + llo) * 16 + lhi * 8];
    }
    f4 hacc0 = {0,0,0,0}, hacc1 = {0,0,0,0};
    hacc0 = MFMA16(af, v0f, hacc0);
    hacc1 = MFMA16(af, v1f, hacc1);

    // 7. write H into shared Hcat [16][128] (swizzled), barrier, out-projection
#pragma unroll
    for (int nt2 = 0; nt2 < 2; ++nt2) {
      const f4 hv = nt2 ? hacc1 : hacc0;
#pragma unroll
      for (int r = 0; r < 4; ++r) {
        const int t = lhi * 4 + r;
        const int d = wid * 32 + nt2 * 16 + llo;     // global head-dim col 0..127
        const int sl = (d >> 3) ^ (t & 7);
        s_h[t * 128 + sl * 8 + (d & 7)] = (_Float16)hv[r];
      }
    }
    __syncthreads();

    f4 oacc0 = {0,0,0,0}, oacc1 = {0,0,0,0};
#pragma unroll
    for (int ks = 0; ks < 4; ++ks) {
      const int sl = (ks * 4 + lhi) ^ (llo & 7);
      const h8 hf = *(const h8*)&s_h[llo * 128 + sl * 8];
      oacc0 = MFMA16(hf, wof[ks][0], oacc0);
      oacc1 = MFMA16(hf, wof[ks][1], oacc1);
    }
    float* ob = outg + (size_t)b * 2048;
#pragma unroll
    for (int r = 0; r < 4; ++r) {
      const int t = lhi * 4 + r;
      ob[t * 128 + wid * 32 + llo]      = oacc0[r];
      ob[t * 128 + wid * 32 + 16 + llo] = oacc1[r];
    }

    // 8. convert+write the prefetched next batch into the x buffer.
    // Safe single-buffered: every wave's step-2 reads of this iteration are
    // already separated from these writes by the step-7 barrier.
    if (hasNext) {
      const int m  = tid >> 4;
      const int sl = (tid & 15) ^ (m & 7);
      const float f[8] = {pa.x, pa.y, pa.z, pa.w, pb.x, pb.y, pb.z, pb.w};
      h8 hi, lo;
#pragma unroll
      for (int j = 0; j < 8; ++j) {
        const _Float16 h = (_Float16)f[j];
        hi[j] = h;
        lo[j] = (_Float16)(f[j] - (float)h);
      }
      *(h8*)&s_xh[m * 128 + sl * 8] = hi;
      *(h8*)&s_xl[m * 128 + sl * 8] = lo;
    }
    __syncthreads();   // protects Hcat reuse and x buffer publish
  }
}

extern "C" void kernel_launch(void* const* d_in, const int* in_sizes, int n_in,
                              void* d_out, int out_size, void* d_ws, size_t ws_size,
                              hipStream_t stream) {
  const float* x  = (const float*)d_in[0];
  const float* wq = (const float*)d_in[1];
  const float* wk = (const float*)d_in[2];
  const float* wv = (const float*)d_in[3];
  const float* wo = (const float*)d_in[4];
  float* out = (float*)d_out;
  attn16<<<NWG, 256, 0, stream>>>(x, wq, wk, wv, wo, out);
}

// Round 4
// 293.549 us; speedup vs baseline: 1.2494x; 1.2494x over previous
//
#include <hip/hip_runtime.h>

// x: [16384,16,128] f32; w_q/k/v: [4,128,32] f32; w_o: [4,32,128] f32
// out: [16384,16,128] f32
#define BATCHES 16384
#define BPW     8               // batches per workgroup
#define NWG     (BATCHES / BPW) // 2048 workgroups, 256 threads each

typedef __attribute__((ext_vector_type(8))) _Float16 h8;
typedef __attribute__((ext_vector_type(4))) _Float16 h4;
typedef __attribute__((ext_vector_type(4))) float f4;

#define MFMA32(a, b, c) __builtin_amdgcn_mfma_f32_16x16x32_f16((a), (b), (c), 0, 0, 0)
#define MFMA16(a, b, c) __builtin_amdgcn_mfma_f32_16x16x16f16((a), (b), (c), 0, 0, 0)

// Orientation-chained design: every MFMA's C-layout (row=(lane>>4)*4+reg,
// col=lane&15) coincides with the 16x16x16 A/B-frag layout (k=(lane>>4)*4+j,
// m/n=lane&15), so stage outputs feed the next stage's operands in-register:
//   Q^T,K^T = mfma(A=W-frag, B=x-frag)      -> C[d][t]  (d on regs, t=llo)
//   S^T     = mfma(A=K^T, B=Q^T) 2 ksteps   -> C[t'][s] (t' on regs, s=llo)
//   softmax over t' = 3 in-lane ops + shfl_xor(16) + shfl_xor(32)
//   H^T     = mfma(A=V (normal C-layout), B=softmax(S^T))  -> C[d][s]
//   out^T   = mfma(A=Wo^T-frag, B=H^T from LDS) -> float4-contig stores
// Only ONE LDS bounce (H^T, cross-wave head concat) and ONE barrier per batch.

__global__ __launch_bounds__(256, 1)
void attn16(const float* __restrict__ xg,
            const float* __restrict__ wq,
            const float* __restrict__ wk,
            const float* __restrict__ wv,
            const float* __restrict__ wo,
            float* __restrict__ outg)
{
  // LDS: 24.5 KB
  __shared__ __align__(16) _Float16 s_xh[2][2048];  // x hi [16][128], swizzled, dbuf
  __shared__ __align__(16) _Float16 s_xl[2][2048];  // x lo
  __shared__ __align__(16) _Float16 s_ht[2][2048];  // H^T cat as [s][hd] f16, swizzled, dbuf

  const int tid  = threadIdx.x;
  const int wid  = tid >> 6;   // wave id == head id (proj) == o-col-slice (out-proj)
  const int lane = tid & 63;
  const int lhi  = lane >> 4;  // 0..3
  const int llo  = lane & 15;  // 0..15

  const float scale = 0.17677669529663687f;  // 32^-0.5, folded into wq pre-split

  // ---- resident weight fragments (A-frag == B-frag layout for 16x16x32) ----
  // lane holds W[e=ks*32+lhi*8+j][d=mt*16+llo], j=0..7
  h8 wqh[4][2], wql[4][2], wkh[4][2], wkl[4][2], wvf[4][2];
#pragma unroll
  for (int ks = 0; ks < 4; ++ks) {
#pragma unroll
    for (int mt = 0; mt < 2; ++mt) {
#pragma unroll
      for (int j = 0; j < 8; ++j) {
        const int e = ks * 32 + lhi * 8 + j;
        const int d = mt * 16 + llo;
        const float q = wq[(size_t)wid * 4096 + e * 32 + d] * scale;
        const float k = wk[(size_t)wid * 4096 + e * 32 + d];
        const float v = wv[(size_t)wid * 4096 + e * 32 + d];
        const _Float16 qh = (_Float16)q;
        const _Float16 kh = (_Float16)k;
        wqh[ks][mt][j] = qh;
        wql[ks][mt][j] = (_Float16)(q - (float)qh);
        wkh[ks][mt][j] = kh;
        wkl[ks][mt][j] = (_Float16)(k - (float)kh);
        wvf[ks][mt][j] = (_Float16)v;
      }
    }
  }
  // Wo^T A-frags for out^T: lane holds wo[hd=ks*16+lhi*4+j][o=(wid*2+mt)*16+llo]
  h4 wof[8][2];
#pragma unroll
  for (int ks = 0; ks < 8; ++ks) {
#pragma unroll
    for (int mt = 0; mt < 2; ++mt) {
#pragma unroll
      for (int j = 0; j < 4; ++j) {
        const int hd = ks * 16 + lhi * 4 + j;             // h = hd>>5, d = hd&31
        const int o  = (wid * 2 + mt) * 16 + llo;
        wof[ks][mt][j] = (_Float16)wo[(size_t)(hd >> 5) * 4096 + (hd & 31) * 128 + o];
      }
    }
  }

  const int b0 = blockIdx.x * BPW;

  // ---- prologue: stage batch b0 into x buf 0 ----
  {
    const float4* src = (const float4*)(xg + (size_t)b0 * 2048);
    const float4 a = src[tid * 2 + 0];
    const float4 b = src[tid * 2 + 1];
    const int m  = tid >> 4;                 // seq row 0..15
    const int sl = (tid & 15) ^ (m & 7);     // swizzled 8-half slot
    const float f[8] = {a.x, a.y, a.z, a.w, b.x, b.y, b.z, b.w};
    h8 hi, lo;
#pragma unroll
    for (int j = 0; j < 8; ++j) {
      const _Float16 h = (_Float16)f[j];
      hi[j] = h;
      lo[j] = (_Float16)(f[j] - (float)h);
    }
    *(h8*)&s_xh[0][m * 128 + sl * 8] = hi;
    *(h8*)&s_xl[0][m * 128 + sl * 8] = lo;
  }
  __syncthreads();

  int cur = 0;
#pragma unroll 1
  for (int bi = 0; bi < BPW; ++bi) {
    const int b = b0 + bi;
    const bool hasNext = (bi + 1 < BPW);

    // 1. issue next-batch prefetch (landed into x buf cur^1 at step 7)
    float4 pa = {}, pb = {};
    if (hasNext) {
      const float4* src = (const float4*)(xg + (size_t)(b + 1) * 2048);
      pa = src[tid * 2 + 0];
      pb = src[tid * 2 + 1];
    }

    // 2. x fragments (shared by Q^T/K^T as B-operand and V as A-operand)
    h8 xh[4], xl[4];
#pragma unroll
    for (int ks = 0; ks < 4; ++ks) {
      const int sl = (ks * 4 + lhi) ^ (llo & 7);
      xh[ks] = *(const h8*)&s_xh[cur][llo * 128 + sl * 8];
      xl[ks] = *(const h8*)&s_xl[cur][llo * 128 + sl * 8];
    }

    // 3. projections: Q^T,K^T swapped-orientation (split 3-product), V normal
    f4 qt[2] = {{0,0,0,0},{0,0,0,0}};
    f4 kt[2] = {{0,0,0,0},{0,0,0,0}};
    f4 vv[2] = {{0,0,0,0},{0,0,0,0}};
#pragma unroll
    for (int ks = 0; ks < 4; ++ks) {
#pragma unroll
      for (int mt = 0; mt < 2; ++mt) {
        qt[mt] = MFMA32(wqh[ks][mt], xh[ks], qt[mt]);
        qt[mt] = MFMA32(wql[ks][mt], xh[ks], qt[mt]);
        qt[mt] = MFMA32(wqh[ks][mt], xl[ks], qt[mt]);
        kt[mt] = MFMA32(wkh[ks][mt], xh[ks], kt[mt]);
        kt[mt] = MFMA32(wkl[ks][mt], xh[ks], kt[mt]);
        kt[mt] = MFMA32(wkh[ks][mt], xl[ks], kt[mt]);
        vv[mt] = MFMA32(xh[ks], wvf[ks][mt], vv[mt]);
      }
    }

    // 4. in-register hi/lo split of Q^T,K^T; V to f16. C-layout == next frag layout.
    h4 qth[2], qtl[2], kth[2], ktl[2], vh[2];
#pragma unroll
    for (int mt = 0; mt < 2; ++mt) {
#pragma unroll
      for (int j = 0; j < 4; ++j) {
        _Float16 h;
        h = (_Float16)qt[mt][j]; qth[mt][j] = h; qtl[mt][j] = (_Float16)(qt[mt][j] - (float)h);
        h = (_Float16)kt[mt][j]; kth[mt][j] = h; ktl[mt][j] = (_Float16)(kt[mt][j] - (float)h);
        vh[mt][j] = (_Float16)vv[mt][j];
      }
    }

    // 5. S^T = K·Q^T (scale pre-folded): 2 ksteps x 3 split products, 16x16x16
    f4 st = {0,0,0,0};
#pragma unroll
    for (int ks2 = 0; ks2 < 2; ++ks2) {
      st = MFMA16(kth[ks2], qth[ks2], st);
      st = MFMA16(ktl[ks2], qth[ks2], st);
      st = MFMA16(kth[ks2], qtl[ks2], st);
    }

    // 6. softmax over t' (rows of S^T): 4-reg reduce + shfl_xor(16,32)
    float mx = fmaxf(fmaxf(st[0], st[1]), fmaxf(st[2], st[3]));
    mx = fmaxf(mx, __shfl_xor(mx, 16));
    mx = fmaxf(mx, __shfl_xor(mx, 32));
    const float p0 = __expf(st[0] - mx);
    const float p1 = __expf(st[1] - mx);
    const float p2 = __expf(st[2] - mx);
    const float p3 = __expf(st[3] - mx);
    float sm = p0 + p1 + p2 + p3;
    sm += __shfl_xor(sm, 16);
    sm += __shfl_xor(sm, 32);
    const float rinv = __builtin_amdgcn_rcpf(sm);
    h4 an;
    an[0] = (_Float16)(p0 * rinv);
    an[1] = (_Float16)(p1 * rinv);
    an[2] = (_Float16)(p2 * rinv);
    an[3] = (_Float16)(p3 * rinv);

    // 7. H^T = V^T·A^T: A-operand = V C-layout, B-operand = softmax output. Direct.
    f4 ht0 = {0,0,0,0}, ht1 = {0,0,0,0};
    ht0 = MFMA16(vh[0], an, ht0);
    ht1 = MFMA16(vh[1], an, ht1);

    // 8. write H^T [s][hd] f16 to LDS (8B-unit XOR swizzle); also publish
    //    prefetched x into buf cur^1. Both pre-barrier.
#pragma unroll
    for (int mt = 0; mt < 2; ++mt) {
      const f4 hv = mt ? ht1 : ht0;
      h4 hh;
#pragma unroll
      for (int j = 0; j < 4; ++j) hh[j] = (_Float16)hv[j];
      const int u = (wid * 8 + mt * 4 + lhi) ^ ((llo & 7) << 2);
      *(h4*)&s_ht[cur][llo * 128 + u * 4] = hh;
    }
    if (hasNext) {
      const int m  = tid >> 4;
      const int sl = (tid & 15) ^ (m & 7);
      const float f[8] = {pa.x, pa.y, pa.z, pa.w, pb.x, pb.y, pb.z, pb.w};
      h8 hi, lo;
#pragma unroll
      for (int j = 0; j < 8; ++j) {
        const _Float16 h = (_Float16)f[j];
        hi[j] = h;
        lo[j] = (_Float16)(f[j] - (float)h);
      }
      *(h8*)&s_xh[cur ^ 1][m * 128 + sl * 8] = hi;
      *(h8*)&s_xl[cur ^ 1][m * 128 + sl * 8] = lo;
    }
    __syncthreads();  // the only barrier per batch
    // Hazards: H^T write(i)/read(i) split by this barrier; write(i+2) into the
    // same buffer sits behind barrier(i+1), which all waves reach only after
    // finishing read(i) (program order). x buf: write(i+1 data, pre-barrier i)
    // vs read(i+1) (post-barrier i) OK; write(i+2 data) at iter i+1 pre-barrier
    // (i+1) vs read(i) done pre-barrier(i) OK.

    // 9. out^T = Wo^T·H^T_cat: 8 ksteps (hd) x 2 o-mtiles, B-frags from LDS
    f4 oa0 = {0,0,0,0}, oa1 = {0,0,0,0};
#pragma unroll
    for (int ks = 0; ks < 8; ++ks) {
      const int u = (ks * 4 + lhi) ^ ((llo & 7) << 2);
      const h4 hf = *(const h4*)&s_ht[cur][llo * 128 + u * 4];
      oa0 = MFMA16(wof[ks][0], hf, oa0);
      oa1 = MFMA16(wof[ks][1], hf, oa1);
    }
    // C rows are o-contiguous -> float4 stores. out[b][s=llo][o]
    float* ob = outg + (size_t)b * 2048 + llo * 128 + wid * 32 + lhi * 4;
    *(float4*)&ob[0]  = *(const float4*)&oa0;
    *(float4*)&ob[16] = *(const float4*)&oa1;

    cur ^= 1;
  }
}

extern "C" void kernel_launch(void* const* d_in, const int* in_sizes, int n_in,
                              void* d_out, int out_size, void* d_ws, size_t ws_size,
                              hipStream_t stream) {
  const float* x  = (const float*)d_in[0];
  const float* wq = (const float*)d_in[1];
  const float* wk = (const float*)d_in[2];
  const float* wv = (const float*)d_in[3];
  const float* wo = (const float*)d_in[4];
  float* out = (float*)d_out;
  attn16<<<NWG, 256, 0, stream>>>(x, wq, wk, wv, wo, out);
}